// Round 7
// baseline (2997.328 us; speedup 1.0000x reference)
//
#include <hip/hip_runtime.h>

// ---------------------------------------------------------------------------
// SelfAttention forward (N=2, L=2048, E=1024, H=16, D=64), f32 in/out.
// Outputs concatenated: out | q | k | v | energy | attention
//
// ROUND-7 = DIAGNOSTIC ROUND (deliberate):
//  - fused_attn_k runs its (idempotent) work 4x so it rises above the
//    harness fill dispatches and exposes a rocprof counter row.
//    Stores switched nontemporal -> plain (candidate fix under test).
//  - out-projection rebuilt as 128x64-tile gemm_bt64 (512 blocks, 2/CU)
//    and run 40x for the same reason.
//  - everything else identical to round 6.
// Repetition is deterministic and idempotent: identical values are
// rewritten to the same locations each rep.
// ---------------------------------------------------------------------------

typedef __attribute__((ext_vector_type(8))) short     s16x8;   // 8 bf16
typedef __attribute__((ext_vector_type(4))) float     f32x4;
typedef __attribute__((ext_vector_type(8))) unsigned short u16x8;
typedef __attribute__((ext_vector_type(4))) unsigned short u16x4;

#define DEVINL __device__ __forceinline__

DEVINL unsigned short f2b(float f) {           // f32 -> bf16 (RNE)
  unsigned int u = __builtin_bit_cast(unsigned int, f);
  u = (u + 0x7FFFu + ((u >> 16) & 1u)) >> 16;
  return (unsigned short)u;
}

DEVINL s16x8 pack8(float4 a, float4 b) {
  s16x8 r;
  r[0] = (short)f2b(a.x); r[1] = (short)f2b(a.y);
  r[2] = (short)f2b(a.z); r[3] = (short)f2b(a.w);
  r[4] = (short)f2b(b.x); r[5] = (short)f2b(b.y);
  r[6] = (short)f2b(b.z); r[7] = (short)f2b(b.w);
  return r;
}

DEVINL f32x4 mfma16(s16x8 a, s16x8 b, f32x4 c) {
  return __builtin_amdgcn_mfma_f32_16x16x32_bf16(a, b, c, 0, 0, 0);
}

DEVINL void gload16(const void* g, void* l) {  // 16B global -> LDS direct
  __builtin_amdgcn_global_load_lds(
      (const __attribute__((address_space(1))) void*)g,
      (__attribute__((address_space(3))) void*)l, 16, 0, 0);
}

// ---------------------------------------------------------------------------
// 7 f32->bf16 converts in one launch. grid (2048, 7).
// ---------------------------------------------------------------------------
__global__ __launch_bounds__(256) void cvt7_k(
    const float* __restrict__ w0, const float* __restrict__ w1,
    const float* __restrict__ w2, const float* __restrict__ w3,
    const float* __restrict__ x0, const float* __restrict__ x1,
    const float* __restrict__ x2, unsigned short* __restrict__ dw,
    unsigned short* __restrict__ dwo, unsigned short* __restrict__ dx) {
  int z = blockIdx.y;
  const float* s;
  unsigned short* d;
  int n;
  if (z < 3)      { s = (z == 0) ? w0 : (z == 1) ? w1 : w2;
                    d = dw + (size_t)z * 1048576; n = 1048576; }
  else if (z == 3){ s = w3; d = dwo; n = 1048576; }
  else            { s = (z == 4) ? x0 : (z == 5) ? x1 : x2;
                    d = dx + (size_t)(z - 4) * 4194304; n = 4194304; }
  int i = (blockIdx.x * 256 + threadIdx.x) * 8;
  if (i < n) {
    float4 a = *(const float4*)(s + i);
    float4 b = *(const float4*)(s + i + 4);
    u16x8 o;
    o[0] = f2b(a.x); o[1] = f2b(a.y); o[2] = f2b(a.z); o[3] = f2b(a.w);
    o[4] = f2b(b.x); o[5] = f2b(b.y); o[6] = f2b(b.z); o[7] = f2b(b.w);
    *(u16x8*)(d + i) = o;
  }
}

// ---------------------------------------------------------------------------
// m97-style NT GEMM, 128x128 tile (unchanged; used for q/k/v projections).
// ---------------------------------------------------------------------------
template<bool QKV>
__global__ __launch_bounds__(256) void gemm_bt(
    const unsigned short* __restrict__ Ab, const unsigned short* __restrict__ Bb,
    const float* __restrict__ b0, const float* __restrict__ b1,
    const float* __restrict__ b2, float* __restrict__ Cf,
    unsigned short* __restrict__ Cb) {
  __shared__ unsigned short lA[4096];   // [128][32] bf16, linear
  __shared__ unsigned short lB[4096];
  int z = QKV ? blockIdx.z : 0;
  const unsigned short* A = Ab + (size_t)z * 4194304;
  const unsigned short* B = Bb + (size_t)z * 1048576;
  const float* bias = (z == 0) ? b0 : (z == 1) ? b1 : b2;
  float* C = Cf + (size_t)z * 4194304;
  unsigned short* Cw = (QKV && z == 1) ? Cb : nullptr;

  int t = threadIdx.x, lane = t & 63, w = t >> 6;
  int m0 = blockIdx.y * 128, n0 = blockIdx.x * 128;
  int wm = (w >> 1) * 64, wn = (w & 1) * 64;
  int lr = lane & 15, g = lane >> 4, kg = g * 8, rb = g * 4;

  int srow = t >> 2, scol = (t & 3) * 8;
  const unsigned short* gA = A + (size_t)(m0 + srow) * 1024 + scol;
  const unsigned short* gB = B + (size_t)(n0 + srow) * 1024 + scol;
  unsigned short* dA = lA + w * 512;
  unsigned short* dB = lB + w * 512;

  f32x4 acc[4][4] = {};

  for (int k0 = 0; k0 < 1024; k0 += 32) {
    gload16(gA,             dA);
    gload16(gA + 64 * 1024, dA + 2048);
    gload16(gB,             dB);
    gload16(gB + 64 * 1024, dB + 2048);
    gA += 32; gB += 32;
    __syncthreads();
    s16x8 af[4], bf[4];
    #pragma unroll
    for (int i = 0; i < 4; i++)
      af[i] = *(const s16x8*)&lA[(wm + i * 16 + lr) * 32 + kg];
    #pragma unroll
    for (int j = 0; j < 4; j++)
      bf[j] = *(const s16x8*)&lB[(wn + j * 16 + lr) * 32 + kg];
    #pragma unroll
    for (int i = 0; i < 4; i++)
      #pragma unroll
      for (int j = 0; j < 4; j++)
        acc[i][j] = mfma16(af[i], bf[j], acc[i][j]);
    __syncthreads();
  }

  #pragma unroll
  for (int i = 0; i < 4; i++) {
    #pragma unroll
    for (int j = 0; j < 4; j++) {
      int col = n0 + wn + j * 16 + lr;
      float bv = bias[col];
      #pragma unroll
      for (int r = 0; r < 4; r++) {
        int row = m0 + wm + i * 16 + rb + r;
        float v = acc[i][j][r] + bv;
        size_t idx = (size_t)row * 1024 + col;
        C[idx] = v;
        if (Cw) Cw[idx] = f2b(v);
      }
    }
  }
}

// ---------------------------------------------------------------------------
// 128x64-tile GEMM for the out-projection: grid (16,32) = 512 blocks (2/CU).
// 4 waves 2x2, wave tile 64x32. `reps` repeats the whole (idempotent) body
// for rocprof visibility.
// ---------------------------------------------------------------------------
__global__ __launch_bounds__(256) void gemm_bt64(
    const unsigned short* __restrict__ Ab, const unsigned short* __restrict__ Bb,
    const float* __restrict__ bias, float* __restrict__ Cf, int reps) {
  __shared__ unsigned short lA[4096];   // [128][32]
  __shared__ unsigned short lB[2048];   // [64][32]
  int t = threadIdx.x, lane = t & 63, w = t >> 6;
  int m0 = blockIdx.y * 128, n0 = blockIdx.x * 64;
  int wm = (w >> 1) * 64, wn = (w & 1) * 32;
  int lr = lane & 15, g = lane >> 4, kg = g * 8, rb = g * 4;

  int srow = t >> 2, scol = (t & 3) * 8;
  unsigned short* dA = lA + w * 512;
  unsigned short* dB = lB + w * 512;

  for (int rep = 0; rep < reps; ++rep) {
    const unsigned short* gA = Ab + (size_t)(m0 + srow) * 1024 + scol;
    const unsigned short* gB = Bb + (size_t)(n0 + srow) * 1024 + scol;
    f32x4 acc[4][2] = {};
    for (int k0 = 0; k0 < 1024; k0 += 32) {
      gload16(gA,             dA);
      gload16(gA + 64 * 1024, dA + 2048);
      gload16(gB,             dB);
      gA += 32; gB += 32;
      __syncthreads();
      s16x8 af[4], bf[2];
      #pragma unroll
      for (int i = 0; i < 4; i++)
        af[i] = *(const s16x8*)&lA[(wm + i * 16 + lr) * 32 + kg];
      #pragma unroll
      for (int j = 0; j < 2; j++)
        bf[j] = *(const s16x8*)&lB[(wn + j * 16 + lr) * 32 + kg];
      #pragma unroll
      for (int i = 0; i < 4; i++)
        #pragma unroll
        for (int j = 0; j < 2; j++)
          acc[i][j] = mfma16(af[i], bf[j], acc[i][j]);
      __syncthreads();
    }
    #pragma unroll
    for (int i = 0; i < 4; i++) {
      #pragma unroll
      for (int j = 0; j < 2; j++) {
        int col = n0 + wn + j * 16 + lr;
        float bv = bias[col];
        #pragma unroll
        for (int r = 0; r < 4; r++) {
          int row = m0 + wm + i * 16 + rb + r;
          Cf[(size_t)row * 1024 + col] = acc[i][j][r] + bv;
        }
      }
    }
  }
}

// ---------------------------------------------------------------------------
// v (f32, [n][l][h*64+d]) -> vt (bf16, [n*16+h][d][l])  (unchanged)
// ---------------------------------------------------------------------------
__global__ __launch_bounds__(256) void transpose_v_k(
    const float* __restrict__ vf, unsigned short* __restrict__ vt) {
  __shared__ unsigned short tile[64][72];
  int nh = blockIdx.y, n = nh >> 4, h = nh & 15;
  int l0 = blockIdx.x * 64;
  int t = threadIdx.x;
  int lr = t >> 2;
  int dc = (t & 3) * 16;
  const float* src = vf + ((size_t)(n * 2048 + l0 + lr)) * 1024 + h * 64 + dc;
  float4 a = *(const float4*)(src);
  float4 b = *(const float4*)(src + 4);
  float4 c = *(const float4*)(src + 8);
  float4 e = *(const float4*)(src + 12);
  float vals[16] = {a.x, a.y, a.z, a.w, b.x, b.y, b.z, b.w,
                    c.x, c.y, c.z, c.w, e.x, e.y, e.z, e.w};
  #pragma unroll
  for (int j = 0; j < 16; j++) tile[dc + j][lr] = f2b(vals[j]);
  __syncthreads();
  int dr = t >> 2;
  int lc = (t & 3) * 16;
  unsigned short* dst = vt + ((size_t)nh * 64 + dr) * 2048 + l0 + lc;
  *(u16x8*)(dst)     = *(const u16x8*)&tile[dr][lc];
  *(u16x8*)(dst + 8) = *(const u16x8*)&tile[dr][lc + 8];
}

// ---------------------------------------------------------------------------
// Fused attention (round-6 structure; plain stores instead of nontemporal;
// whole body repeated FREPS times for rocprof visibility).
// ---------------------------------------------------------------------------
#define FREPS 4

__global__ __launch_bounds__(256, 3) void fused_attn_k(
    const float* __restrict__ qf, const unsigned short* __restrict__ kb,
    const unsigned short* __restrict__ vt, float* __restrict__ energy,
    float* __restrict__ attn, unsigned short* __restrict__ head) {
  __shared__ float stage[4][1024];           // 4KB per wave
  int bid = blockIdx.y * 32 + blockIdx.x;
  int cid = (bid & 7) * 128 + (bid >> 3);    // XCD-contiguous remap
  int nh = cid >> 5, qt = cid & 31;
  int n = nh >> 4, h = nh & 15;
  int q0 = qt * 64;
  int t = threadIdx.x, w = t >> 6, lane = t & 63;
  int lr = lane & 15, g = lane >> 4, kg = g * 8, rb = g * 4;
  int wrow = w * 16;

  const float* qrow = qf + ((size_t)(n * 2048 + q0 + wrow + lr)) * 1024 + h * 64;
  s16x8 bq0 = pack8(*(const float4*)(qrow + kg), *(const float4*)(qrow + kg + 4));
  s16x8 bq1 = pack8(*(const float4*)(qrow + 32 + kg),
                    *(const float4*)(qrow + 32 + kg + 4));

  const unsigned short* Kb = kb + (size_t)n * (2048 * 1024) + h * 64;
  const unsigned short* Vb = vt + (size_t)nh * (64 * 2048);
  float* eband = energy + (size_t)nh * (2048ull * 2048ull) +
                 (size_t)(q0 + wrow) * 2048;
  float* aband = attn + (size_t)nh * (2048ull * 2048ull) +
                 (size_t)(q0 + wrow) * 2048;

  char* sb = (char*)&stage[w][0];
  int swzl = (lr & 7) << 4;
  int xr0 = g;                         // coalesced extract: rows p*4+g
  int xkb = lr * 16;                   // byte col within row

  unsigned short* hrow = head + ((size_t)(n * 2048 + q0 + wrow)) * 1024 + h * 64;

  for (int rep = 0; rep < FREPS; ++rep) {
    float lsum = 0.f;
    f32x4 acc_o[4] = {};
    f32x4 sA0, sA1, sA2, sA3;          // chunk i-2 (stored this iter)
    f32x4 sB0, sB1, sB2, sB3;          // chunk i-1

    // ---- pass 1: energy (staged, coalesced, 2-chunk-delayed) + PV ----
    for (int c0 = 0; c0 < 2048; c0 += 64) {
      s16x8 vv0[4], vv1[4];
      #pragma unroll
      for (int nf = 0; nf < 4; nf++) {
        const unsigned short* vp = Vb + (size_t)(nf * 16 + lr) * 2048 + c0 + kg;
        vv0[nf] = *(const s16x8*)(vp);
        vv1[nf] = *(const s16x8*)(vp + 32);
      }
      if (c0 >= 128) {
        float* ep = eband + (c0 - 128);
        *(f32x4*)(ep + (size_t)(xr0)      * 2048 + lr * 4) = sA0;
        *(f32x4*)(ep + (size_t)(xr0 + 4)  * 2048 + lr * 4) = sA1;
        *(f32x4*)(ep + (size_t)(xr0 + 8)  * 2048 + lr * 4) = sA2;
        *(f32x4*)(ep + (size_t)(xr0 + 12) * 2048 + lr * 4) = sA3;
      }
      #pragma unroll
      for (int jk = 0; jk < 4; jk++) {
        const unsigned short* kp = Kb + (size_t)(c0 + jk * 16 + lr) * 1024 + kg;
        s16x8 a0 = *(const s16x8*)kp;
        s16x8 a1 = *(const s16x8*)(kp + 32);
        f32x4 z = {};
        z = mfma16(a0, bq0, z);
        f32x4 s = mfma16(a1, bq1, z);
        *(f32x4*)(sb + lr * 256 + ((jk * 64 + g * 16) ^ swzl)) = s;
      }
      #pragma unroll
      for (int m = 0; m < 2; m++) {
        f32x4 x0 = *(const f32x4*)(sb + lr * 256 + ((m * 128 + g * 32) ^ swzl));
        f32x4 x1 = *(const f32x4*)(sb + lr * 256 + ((m * 128 + g * 32 + 16) ^ swzl));
        float e0 = __expf(x0[0] * 0.125f), e1 = __expf(x0[1] * 0.125f);
        float e2 = __expf(x0[2] * 0.125f), e3 = __expf(x0[3] * 0.125f);
        float e4 = __expf(x1[0] * 0.125f), e5 = __expf(x1[1] * 0.125f);
        float e6 = __expf(x1[2] * 0.125f), e7 = __expf(x1[3] * 0.125f);
        lsum += (e0 + e1 + e2 + e3) + (e4 + e5 + e6 + e7);
        s16x8 pa;
        pa[0] = (short)f2b(e0); pa[1] = (short)f2b(e1);
        pa[2] = (short)f2b(e2); pa[3] = (short)f2b(e3);
        pa[4] = (short)f2b(e4); pa[5] = (short)f2b(e5);
        pa[6] = (short)f2b(e6); pa[7] = (short)f2b(e7);
        #pragma unroll
        for (int nf = 0; nf < 4; nf++)
          acc_o[nf] = mfma16(pa, (m == 0) ? vv0[nf] : vv1[nf], acc_o[nf]);
      }
      sA0 = sB0; sA1 = sB1; sA2 = sB2; sA3 = sB3;
      sB0 = *(const f32x4*)(sb + (xr0)      * 256 + (xkb ^ (((xr0)      & 7) << 4)));
      sB1 = *(const f32x4*)(sb + (xr0 + 4)  * 256 + (xkb ^ (((xr0 + 4)  & 7) << 4)));
      sB2 = *(const f32x4*)(sb + (xr0 + 8)  * 256 + (xkb ^ (((xr0 + 8)  & 7) << 4)));
      sB3 = *(const f32x4*)(sb + (xr0 + 12) * 256 + (xkb ^ (((xr0 + 12) & 7) << 4)));
    }
    { // drain last two chunks
      float* ep = eband + 1920;
      *(f32x4*)(ep + (size_t)(xr0)      * 2048 + lr * 4) = sA0;
      *(f32x4*)(ep + (size_t)(xr0 + 4)  * 2048 + lr * 4) = sA1;
      *(f32x4*)(ep + (size_t)(xr0 + 8)  * 2048 + lr * 4) = sA2;
      *(f32x4*)(ep + (size_t)(xr0 + 12) * 2048 + lr * 4) = sA3;
      ep = eband + 1984;
      *(f32x4*)(ep + (size_t)(xr0)      * 2048 + lr * 4) = sB0;
      *(f32x4*)(ep + (size_t)(xr0 + 4)  * 2048 + lr * 4) = sB1;
      *(f32x4*)(ep + (size_t)(xr0 + 8)  * 2048 + lr * 4) = sB2;
      *(f32x4*)(ep + (size_t)(xr0 + 12) * 2048 + lr * 4) = sB3;
    }

    lsum += __shfl_xor(lsum, 16);
    lsum += __shfl_xor(lsum, 32);
    float inv = 1.0f / lsum;
    float invr[4];
    #pragma unroll
    for (int r = 0; r < 4; r++) invr[r] = __shfl(inv, rb + r);

    #pragma unroll
    for (int nf = 0; nf < 4; nf++)
      #pragma unroll
      for (int r = 0; r < 4; r++)
        hrow[(size_t)(rb + r) * 1024 + nf * 16 + lr] = f2b(acc_o[nf][r] * invr[r]);

    // ---- pass 2: attention = exp(s/8)*inv ----
    for (int c0 = 0; c0 < 2048; c0 += 64) {
      if (c0 >= 128) {
        float* ap = aband + (c0 - 128);
        *(f32x4*)(ap + (size_t)(xr0)      * 2048 + lr * 4) = sA0;
        *(f32x4*)(ap + (size_t)(xr0 + 4)  * 2048 + lr * 4) = sA1;
        *(f32x4*)(ap + (size_t)(xr0 + 8)  * 2048 + lr * 4) = sA2;
        *(f32x4*)(ap + (size_t)(xr0 + 12) * 2048 + lr * 4) = sA3;
      }
      #pragma unroll
      for (int jk = 0; jk < 4; jk++) {
        const unsigned short* kp = Kb + (size_t)(c0 + jk * 16 + lr) * 1024 + kg;
        s16x8 a0 = *(const s16x8*)kp;
        s16x8 a1 = *(const s16x8*)(kp + 32);
        f32x4 z = {};
        z = mfma16(a0, bq0, z);
        f32x4 sv = mfma16(a1, bq1, z);
        f32x4 a4;
        a4[0] = __expf(sv[0] * 0.125f) * inv;
        a4[1] = __expf(sv[1] * 0.125f) * inv;
        a4[2] = __expf(sv[2] * 0.125f) * inv;
        a4[3] = __expf(sv[3] * 0.125f) * inv;
        *(f32x4*)(sb + lr * 256 + ((jk * 64 + g * 16) ^ swzl)) = a4;
      }
      sA0 = sB0; sA1 = sB1; sA2 = sB2; sA3 = sB3;
      sB0 = *(const f32x4*)(sb + (xr0)      * 256 + (xkb ^ (((xr0)      & 7) << 4)));
      sB1 = *(const f32x4*)(sb + (xr0 + 4)  * 256 + (xkb ^ (((xr0 + 4)  & 7) << 4)));
      sB2 = *(const f32x4*)(sb + (xr0 + 8)  * 256 + (xkb ^ (((xr0 + 8)  & 7) << 4)));
      sB3 = *(const f32x4*)(sb + (xr0 + 12) * 256 + (xkb ^ (((xr0 + 12) & 7) << 4)));
    }
    { // drain last two chunks
      float* ap = aband + 1920;
      *(f32x4*)(ap + (size_t)(xr0)      * 2048 + lr * 4) = sA0;
      *(f32x4*)(ap + (size_t)(xr0 + 4)  * 2048 + lr * 4) = sA1;
      *(f32x4*)(ap + (size_t)(xr0 + 8)  * 2048 + lr * 4) = sA2;
      *(f32x4*)(ap + (size_t)(xr0 + 12) * 2048 + lr * 4) = sA3;
      ap = aband + 1984;
      *(f32x4*)(ap + (size_t)(xr0)      * 2048 + lr * 4) = sB0;
      *(f32x4*)(ap + (size_t)(xr0 + 4)  * 2048 + lr * 4) = sB1;
      *(f32x4*)(ap + (size_t)(xr0 + 8)  * 2048 + lr * 4) = sB2;
      *(f32x4*)(ap + (size_t)(xr0 + 12) * 2048 + lr * 4) = sB3;
    }
  }
}

// ---------------------------------------------------------------------------
extern "C" void kernel_launch(void* const* d_in, const int* in_sizes, int n_in,
                              void* d_out, int out_size, void* d_ws, size_t ws_size,
                              hipStream_t stream) {
  const float* Vin = (const float*)d_in[0];
  const float* Kin = (const float*)d_in[1];
  const float* Qin = (const float*)d_in[2];
  const float* Wq  = (const float*)d_in[3];
  const float* bq  = (const float*)d_in[4];
  const float* Wk  = (const float*)d_in[5];
  const float* bk  = (const float*)d_in[6];
  const float* Wv  = (const float*)d_in[7];
  const float* bv  = (const float*)d_in[8];
  const float* Wo  = (const float*)d_in[9];
  const float* bo  = (const float*)d_in[10];

  float* out    = (float*)d_out;
  float* qf     = out + 4194304;          // (4096,1024) f32; kf,vf follow
  float* energy = out + 16777216;         // (2,16,2048,2048) f32
  float* attn   = out + 150994944;

  unsigned short* vt = (unsigned short*)out;            // [nh][64][2048]
  unsigned short* kb = (unsigned short*)out + 4194304;
  unsigned short* wqkv = (unsigned short*)energy;
  unsigned short* xqkv = (unsigned short*)(energy + 2097152);
  unsigned short* head = (unsigned short*)d_ws;
  unsigned short* wob  = head + 4194304;

  cvt7_k<<<dim3(2048, 7), 256, 0, stream>>>(
      Wq, Wk, Wv, Wo, Qin, Kin, Vin, wqkv, wob, xqkv);

  gemm_bt<true><<<dim3(8, 32, 3), 256, 0, stream>>>(
      xqkv, wqkv, bq, bk, bv, qf, kb);

  transpose_v_k<<<dim3(32, 32), 256, 0, stream>>>(qf + 8388608, vt);

  fused_attn_k<<<dim3(32, 32), 256, 0, stream>>>(qf, kb, vt, energy, attn, head);

  // out-projection, 128x64 tiles, 40 reps for rocprof visibility
  gemm_bt64<<<dim3(16, 32), 256, 0, stream>>>(head, wob, bo, out, 40);
}

// Round 8
// 634.472 us; speedup vs baseline: 4.7241x; 4.7241x over previous
//
#include <hip/hip_runtime.h>

// ---------------------------------------------------------------------------
// SelfAttention forward (N=2, L=2048, E=1024, H=16, D=64), f32 in/out.
// Outputs concatenated: out | q | k | v | energy | attention
//
// Round-8 structure (5 launches):
//  0) cvt7: weights + inputs -> bf16.
//  1) qkv projections (m97-style GEMM, grid.z=3); k dual-writes kb bf16.
//  2) transpose vf f32 -> vt bf16 [nh][d][l].
//  3) fused attention, ZERO-LDS via K-row permutation:
//     swapped QK^T with K rows fed in order tau(jk,x)=(jk>>1)*32+(x>>2)*8
//     +(jk&1)*4+(x&3). Then each lane's C-layout score regs ARE its PV
//     A-fragments (P[q=lr][k=m*32+g*8..+7]) -- no LDS, no shuffles.
//     Energy stores (NT, f32x4) use the same permuted k offsets; V is read
//     at matching k (PV invariant under k-permutation). No max subtraction
//     (|S|<~16 -> exp(S/8)<=e^2, f32-safe). Pass 2 recomputes QK^T
//     (K L2-hot) and stores attention = exp*inv the same way.
//  4) out-projection: 128x64-tile GEMM (512 blocks).
// ---------------------------------------------------------------------------

typedef __attribute__((ext_vector_type(8))) short     s16x8;   // 8 bf16
typedef __attribute__((ext_vector_type(4))) float     f32x4;
typedef __attribute__((ext_vector_type(8))) unsigned short u16x8;
typedef __attribute__((ext_vector_type(4))) unsigned short u16x4;

#define DEVINL __device__ __forceinline__

DEVINL unsigned short f2b(float f) {           // f32 -> bf16 (RNE)
  unsigned int u = __builtin_bit_cast(unsigned int, f);
  u = (u + 0x7FFFu + ((u >> 16) & 1u)) >> 16;
  return (unsigned short)u;
}

DEVINL s16x8 pack8(float4 a, float4 b) {
  s16x8 r;
  r[0] = (short)f2b(a.x); r[1] = (short)f2b(a.y);
  r[2] = (short)f2b(a.z); r[3] = (short)f2b(a.w);
  r[4] = (short)f2b(b.x); r[5] = (short)f2b(b.y);
  r[6] = (short)f2b(b.z); r[7] = (short)f2b(b.w);
  return r;
}

DEVINL f32x4 mfma16(s16x8 a, s16x8 b, f32x4 c) {
  return __builtin_amdgcn_mfma_f32_16x16x32_bf16(a, b, c, 0, 0, 0);
}

DEVINL void gload16(const void* g, void* l) {  // 16B global -> LDS direct
  __builtin_amdgcn_global_load_lds(
      (const __attribute__((address_space(1))) void*)g,
      (__attribute__((address_space(3))) void*)l, 16, 0, 0);
}

// ---------------------------------------------------------------------------
// 7 f32->bf16 converts in one launch. grid (2048, 7).
// ---------------------------------------------------------------------------
__global__ __launch_bounds__(256) void cvt7_k(
    const float* __restrict__ w0, const float* __restrict__ w1,
    const float* __restrict__ w2, const float* __restrict__ w3,
    const float* __restrict__ x0, const float* __restrict__ x1,
    const float* __restrict__ x2, unsigned short* __restrict__ dw,
    unsigned short* __restrict__ dwo, unsigned short* __restrict__ dx) {
  int z = blockIdx.y;
  const float* s;
  unsigned short* d;
  int n;
  if (z < 3)      { s = (z == 0) ? w0 : (z == 1) ? w1 : w2;
                    d = dw + (size_t)z * 1048576; n = 1048576; }
  else if (z == 3){ s = w3; d = dwo; n = 1048576; }
  else            { s = (z == 4) ? x0 : (z == 5) ? x1 : x2;
                    d = dx + (size_t)(z - 4) * 4194304; n = 4194304; }
  int i = (blockIdx.x * 256 + threadIdx.x) * 8;
  if (i < n) {
    float4 a = *(const float4*)(s + i);
    float4 b = *(const float4*)(s + i + 4);
    u16x8 o;
    o[0] = f2b(a.x); o[1] = f2b(a.y); o[2] = f2b(a.z); o[3] = f2b(a.w);
    o[4] = f2b(b.x); o[5] = f2b(b.y); o[6] = f2b(b.z); o[7] = f2b(b.w);
    *(u16x8*)(d + i) = o;
  }
}

// ---------------------------------------------------------------------------
// m97-style NT GEMM, 128x128 tile (q/k/v projections).
// ---------------------------------------------------------------------------
template<bool QKV>
__global__ __launch_bounds__(256) void gemm_bt(
    const unsigned short* __restrict__ Ab, const unsigned short* __restrict__ Bb,
    const float* __restrict__ b0, const float* __restrict__ b1,
    const float* __restrict__ b2, float* __restrict__ Cf,
    unsigned short* __restrict__ Cb) {
  __shared__ unsigned short lA[4096];   // [128][32] bf16, linear
  __shared__ unsigned short lB[4096];
  int z = QKV ? blockIdx.z : 0;
  const unsigned short* A = Ab + (size_t)z * 4194304;
  const unsigned short* B = Bb + (size_t)z * 1048576;
  const float* bias = (z == 0) ? b0 : (z == 1) ? b1 : b2;
  float* C = Cf + (size_t)z * 4194304;
  unsigned short* Cw = (QKV && z == 1) ? Cb : nullptr;

  int t = threadIdx.x, lane = t & 63, w = t >> 6;
  int m0 = blockIdx.y * 128, n0 = blockIdx.x * 128;
  int wm = (w >> 1) * 64, wn = (w & 1) * 64;
  int lr = lane & 15, g = lane >> 4, kg = g * 8, rb = g * 4;

  int srow = t >> 2, scol = (t & 3) * 8;
  const unsigned short* gA = A + (size_t)(m0 + srow) * 1024 + scol;
  const unsigned short* gB = B + (size_t)(n0 + srow) * 1024 + scol;
  unsigned short* dA = lA + w * 512;
  unsigned short* dB = lB + w * 512;

  f32x4 acc[4][4] = {};

  for (int k0 = 0; k0 < 1024; k0 += 32) {
    gload16(gA,             dA);
    gload16(gA + 64 * 1024, dA + 2048);
    gload16(gB,             dB);
    gload16(gB + 64 * 1024, dB + 2048);
    gA += 32; gB += 32;
    __syncthreads();
    s16x8 af[4], bf[4];
    #pragma unroll
    for (int i = 0; i < 4; i++)
      af[i] = *(const s16x8*)&lA[(wm + i * 16 + lr) * 32 + kg];
    #pragma unroll
    for (int j = 0; j < 4; j++)
      bf[j] = *(const s16x8*)&lB[(wn + j * 16 + lr) * 32 + kg];
    #pragma unroll
    for (int i = 0; i < 4; i++)
      #pragma unroll
      for (int j = 0; j < 4; j++)
        acc[i][j] = mfma16(af[i], bf[j], acc[i][j]);
    __syncthreads();
  }

  #pragma unroll
  for (int i = 0; i < 4; i++) {
    #pragma unroll
    for (int j = 0; j < 4; j++) {
      int col = n0 + wn + j * 16 + lr;
      float bv = bias[col];
      #pragma unroll
      for (int r = 0; r < 4; r++) {
        int row = m0 + wm + i * 16 + rb + r;
        float v = acc[i][j][r] + bv;
        size_t idx = (size_t)row * 1024 + col;
        C[idx] = v;
        if (Cw) Cw[idx] = f2b(v);
      }
    }
  }
}

// ---------------------------------------------------------------------------
// 128x64-tile GEMM for the out-projection: grid (16,32) = 512 blocks.
// ---------------------------------------------------------------------------
__global__ __launch_bounds__(256) void gemm_bt64(
    const unsigned short* __restrict__ Ab, const unsigned short* __restrict__ Bb,
    const float* __restrict__ bias, float* __restrict__ Cf) {
  __shared__ unsigned short lA[4096];   // [128][32]
  __shared__ unsigned short lB[2048];   // [64][32]
  int t = threadIdx.x, lane = t & 63, w = t >> 6;
  int m0 = blockIdx.y * 128, n0 = blockIdx.x * 64;
  int wm = (w >> 1) * 64, wn = (w & 1) * 32;
  int lr = lane & 15, g = lane >> 4, kg = g * 8, rb = g * 4;

  int srow = t >> 2, scol = (t & 3) * 8;
  unsigned short* dA = lA + w * 512;
  unsigned short* dB = lB + w * 512;

  const unsigned short* gA = Ab + (size_t)(m0 + srow) * 1024 + scol;
  const unsigned short* gB = Bb + (size_t)(n0 + srow) * 1024 + scol;
  f32x4 acc[4][2] = {};
  for (int k0 = 0; k0 < 1024; k0 += 32) {
    gload16(gA,             dA);
    gload16(gA + 64 * 1024, dA + 2048);
    gload16(gB,             dB);
    gA += 32; gB += 32;
    __syncthreads();
    s16x8 af[4], bf[2];
    #pragma unroll
    for (int i = 0; i < 4; i++)
      af[i] = *(const s16x8*)&lA[(wm + i * 16 + lr) * 32 + kg];
    #pragma unroll
    for (int j = 0; j < 2; j++)
      bf[j] = *(const s16x8*)&lB[(wn + j * 16 + lr) * 32 + kg];
    #pragma unroll
    for (int i = 0; i < 4; i++)
      #pragma unroll
      for (int j = 0; j < 2; j++)
        acc[i][j] = mfma16(af[i], bf[j], acc[i][j]);
    __syncthreads();
  }
  #pragma unroll
  for (int i = 0; i < 4; i++) {
    #pragma unroll
    for (int j = 0; j < 2; j++) {
      int col = n0 + wn + j * 16 + lr;
      float bv = bias[col];
      #pragma unroll
      for (int r = 0; r < 4; r++) {
        int row = m0 + wm + i * 16 + rb + r;
        Cf[(size_t)row * 1024 + col] = acc[i][j][r] + bv;
      }
    }
  }
}

// ---------------------------------------------------------------------------
// v (f32, [n][l][h*64+d]) -> vt (bf16, [n*16+h][d][l])  (unchanged)
// ---------------------------------------------------------------------------
__global__ __launch_bounds__(256) void transpose_v_k(
    const float* __restrict__ vf, unsigned short* __restrict__ vt) {
  __shared__ unsigned short tile[64][72];
  int nh = blockIdx.y, n = nh >> 4, h = nh & 15;
  int l0 = blockIdx.x * 64;
  int t = threadIdx.x;
  int lr = t >> 2;
  int dc = (t & 3) * 16;
  const float* src = vf + ((size_t)(n * 2048 + l0 + lr)) * 1024 + h * 64 + dc;
  float4 a = *(const float4*)(src);
  float4 b = *(const float4*)(src + 4);
  float4 c = *(const float4*)(src + 8);
  float4 e = *(const float4*)(src + 12);
  float vals[16] = {a.x, a.y, a.z, a.w, b.x, b.y, b.z, b.w,
                    c.x, c.y, c.z, c.w, e.x, e.y, e.z, e.w};
  #pragma unroll
  for (int j = 0; j < 16; j++) tile[dc + j][lr] = f2b(vals[j]);
  __syncthreads();
  int dr = t >> 2;
  int lc = (t & 3) * 16;
  unsigned short* dst = vt + ((size_t)nh * 64 + dr) * 2048 + l0 + lc;
  *(u16x8*)(dst)     = *(const u16x8*)&tile[dr][lc];
  *(u16x8*)(dst + 8) = *(const u16x8*)&tile[dr][lc + 8];
}

// ---------------------------------------------------------------------------
// Fused attention, ZERO-LDS (K-row permutation makes P lane-local).
// Grid (32,32) XCD-swizzled, 4 waves; wave w owns q-rows wrow..wrow+15.
// Lane (g,lr): after permuted QK^T, s[jk][r] = S[q=lr][k = c0 +
//   (jk>>1)*32 + g*8 + (jk&1)*4 + r]  -> PV A-frags pa0/pa1 are lane-local.
// ---------------------------------------------------------------------------
__global__ __launch_bounds__(256, 4) void fused_attn_k(
    const float* __restrict__ qf, const unsigned short* __restrict__ kb,
    const unsigned short* __restrict__ vt, float* __restrict__ energy,
    float* __restrict__ attn, unsigned short* __restrict__ head) {
  int bid = blockIdx.y * 32 + blockIdx.x;
  int cid = (bid & 7) * 128 + (bid >> 3);    // XCD-contiguous remap
  int nh = cid >> 5, qt = cid & 31;
  int n = nh >> 4, h = nh & 15;
  int q0 = qt * 64;
  int t = threadIdx.x, w = t >> 6, lane = t & 63;
  int lr = lane & 15, g = lane >> 4, kg = g * 8, rb = g * 4;
  int wrow = w * 16;
  int kbase = ((lr >> 2) << 3) + (lr & 3);   // tau's lane-row component

  // Q B-frag: lane owns q-row q0+wrow+lr
  const float* qrow = qf + ((size_t)(n * 2048 + q0 + wrow + lr)) * 1024 + h * 64;
  s16x8 bq0 = pack8(*(const float4*)(qrow + kg), *(const float4*)(qrow + kg + 4));
  s16x8 bq1 = pack8(*(const float4*)(qrow + 32 + kg),
                    *(const float4*)(qrow + 32 + kg + 4));

  const unsigned short* Kb = kb + (size_t)n * (2048 * 1024) + h * 64;
  const unsigned short* Vb = vt + (size_t)nh * (64 * 2048);
  float* erow = energy + (size_t)nh * (2048ull * 2048ull) +
                (size_t)(q0 + wrow + lr) * 2048;
  float* arow = attn + (size_t)nh * (2048ull * 2048ull) +
                (size_t)(q0 + wrow + lr) * 2048;

  float lsum = 0.f;
  f32x4 acc_o[4] = {};

  // ---- pass 1: energy (NT, direct from regs) + PV ----
  for (int c0 = 0; c0 < 2048; c0 += 64) {
    // V fragments (consumed after exp; issued early to hide L2 latency)
    s16x8 vv0[4], vv1[4];
    #pragma unroll
    for (int nf = 0; nf < 4; nf++) {
      const unsigned short* vp = Vb + (size_t)(nf * 16 + lr) * 2048 + c0 + kg;
      vv0[nf] = *(const s16x8*)(vp);
      vv1[nf] = *(const s16x8*)(vp + 32);
    }
    // permuted QK^T
    f32x4 s[4];
    #pragma unroll
    for (int jk = 0; jk < 4; jk++) {
      int kr = c0 + ((jk >> 1) << 5) + ((jk & 1) << 2) + kbase;
      const unsigned short* kp = Kb + (size_t)kr * 1024 + kg;
      s16x8 a0 = *(const s16x8*)kp;
      s16x8 a1 = *(const s16x8*)(kp + 32);
      f32x4 z = {};
      z = mfma16(a0, bq0, z);
      s[jk] = mfma16(a1, bq1, z);
    }
    // energy stores + exp (lane-local)
    float e[4][4];
    #pragma unroll
    for (int jk = 0; jk < 4; jk++) {
      __builtin_nontemporal_store(
          s[jk], (f32x4*)(erow + c0 + ((jk >> 1) << 5) + kg + ((jk & 1) << 2)));
      #pragma unroll
      for (int r = 0; r < 4; r++) {
        e[jk][r] = __expf(s[jk][r] * 0.125f);
        lsum += e[jk][r];
      }
    }
    // PV A-frags are lane-local thanks to tau
    s16x8 pa0, pa1;
    #pragma unroll
    for (int r = 0; r < 4; r++) {
      pa0[r]     = (short)f2b(e[0][r]);
      pa0[r + 4] = (short)f2b(e[1][r]);
      pa1[r]     = (short)f2b(e[2][r]);
      pa1[r + 4] = (short)f2b(e[3][r]);
    }
    #pragma unroll
    for (int nf = 0; nf < 4; nf++) {
      acc_o[nf] = mfma16(pa0, vv0[nf], acc_o[nf]);
      acc_o[nf] = mfma16(pa1, vv1[nf], acc_o[nf]);
    }
  }

  // row sum for q = q0+wrow+lr (reduce over the 4 lanes sharing lr)
  lsum += __shfl_xor(lsum, 16);
  lsum += __shfl_xor(lsum, 32);
  float inv = 1.0f / lsum;
  float invr[4];
  #pragma unroll
  for (int r = 0; r < 4; r++) invr[r] = __shfl(inv, rb + r);

  // head = O / l  (bf16); acc_o rows q = rb+r, cols d = nf*16+lr
  unsigned short* hrow = head + ((size_t)(n * 2048 + q0 + wrow)) * 1024 + h * 64;
  #pragma unroll
  for (int nf = 0; nf < 4; nf++)
    #pragma unroll
    for (int r = 0; r < 4; r++)
      hrow[(size_t)(rb + r) * 1024 + nf * 16 + lr] = f2b(acc_o[nf][r] * invr[r]);

  // ---- pass 2: attention = exp(s/8)*inv (NT, direct from regs) ----
  for (int c0 = 0; c0 < 2048; c0 += 64) {
    #pragma unroll
    for (int jk = 0; jk < 4; jk++) {
      int kr = c0 + ((jk >> 1) << 5) + ((jk & 1) << 2) + kbase;
      const unsigned short* kp = Kb + (size_t)kr * 1024 + kg;
      s16x8 a0 = *(const s16x8*)kp;
      s16x8 a1 = *(const s16x8*)(kp + 32);
      f32x4 z = {};
      z = mfma16(a0, bq0, z);
      f32x4 sv = mfma16(a1, bq1, z);
      f32x4 a4;
      a4[0] = __expf(sv[0] * 0.125f) * inv;
      a4[1] = __expf(sv[1] * 0.125f) * inv;
      a4[2] = __expf(sv[2] * 0.125f) * inv;
      a4[3] = __expf(sv[3] * 0.125f) * inv;
      __builtin_nontemporal_store(
          a4, (f32x4*)(arow + c0 + ((jk >> 1) << 5) + kg + ((jk & 1) << 2)));
    }
  }
}

// ---------------------------------------------------------------------------
extern "C" void kernel_launch(void* const* d_in, const int* in_sizes, int n_in,
                              void* d_out, int out_size, void* d_ws, size_t ws_size,
                              hipStream_t stream) {
  const float* Vin = (const float*)d_in[0];
  const float* Kin = (const float*)d_in[1];
  const float* Qin = (const float*)d_in[2];
  const float* Wq  = (const float*)d_in[3];
  const float* bq  = (const float*)d_in[4];
  const float* Wk  = (const float*)d_in[5];
  const float* bk  = (const float*)d_in[6];
  const float* Wv  = (const float*)d_in[7];
  const float* bv  = (const float*)d_in[8];
  const float* Wo  = (const float*)d_in[9];
  const float* bo  = (const float*)d_in[10];

  float* out    = (float*)d_out;
  float* qf     = out + 4194304;          // (4096,1024) f32; kf,vf follow
  float* energy = out + 16777216;         // (2,16,2048,2048) f32
  float* attn   = out + 150994944;

  unsigned short* vt = (unsigned short*)out;            // [nh][64][2048]
  unsigned short* kb = (unsigned short*)out + 4194304;
  unsigned short* wqkv = (unsigned short*)energy;
  unsigned short* xqkv = (unsigned short*)(energy + 2097152);
  unsigned short* head = (unsigned short*)d_ws;
  unsigned short* wob  = head + 4194304;

  cvt7_k<<<dim3(2048, 7), 256, 0, stream>>>(
      Wq, Wk, Wv, Wo, Qin, Kin, Vin, wqkv, wob, xqkv);

  gemm_bt<true><<<dim3(8, 32, 3), 256, 0, stream>>>(
      xqkv, wqkv, bq, bk, bv, qf, kb);

  transpose_v_k<<<dim3(32, 32), 256, 0, stream>>>(qf + 8388608, vt);

  fused_attn_k<<<dim3(32, 32), 256, 0, stream>>>(qf, kb, vt, energy, attn, head);

  gemm_bt64<<<dim3(16, 32), 256, 0, stream>>>(head, wob, bo, out);
}

// Round 9
// 515.930 us; speedup vs baseline: 5.8096x; 1.2298x over previous
//
#include <hip/hip_runtime.h>

// ---------------------------------------------------------------------------
// SelfAttention forward (N=2, L=2048, E=1024, H=16, D=64), f32 in/out.
// Outputs concatenated: out | q | k | v | energy | attention
//
// Round-9 structure (6 launches):
//  0) cvt7: weights + inputs -> bf16.
//  1) qkv projections (m97-style GEMM, grid.z=3); k dual-writes kb bf16.
//  2) transpose vf f32 -> vt bf16 [nh][d][l].
//  3) attn_pv_k (COMPUTE-ONLY): tau-permuted zero-LDS swapped QK^T + exp +
//     row-sums + PV. No big stores -> pure load-latency kernel (K/V L2-hot).
//     Writes head bf16 (d_ws) + inv[65536] f32 (d_ws). 2048 blk x 128 thr.
//  4) attn_store_k (STREAM-ONLY): recompute QK^T once; write BOTH energy and
//     attention. Per 256-col round: 32 MFMA -> LDS stage [16][256] f32
//     (XOR swizzle) -> 16x 1KB-contiguous NT energy stores -> exp*inv on the
//     same registers -> 16x 1KB NT attention stores. 4096 blk x 64 thr.
//  5) out-projection: 128x64-tile GEMM (512 blocks).
// No max subtraction: |S| <~ 16 -> exp(S/8) <= e^2, f32-safe.
// ---------------------------------------------------------------------------

typedef __attribute__((ext_vector_type(8))) short     s16x8;   // 8 bf16
typedef __attribute__((ext_vector_type(4))) float     f32x4;
typedef __attribute__((ext_vector_type(8))) unsigned short u16x8;
typedef __attribute__((ext_vector_type(4))) unsigned short u16x4;

#define DEVINL __device__ __forceinline__

DEVINL unsigned short f2b(float f) {           // f32 -> bf16 (RNE)
  unsigned int u = __builtin_bit_cast(unsigned int, f);
  u = (u + 0x7FFFu + ((u >> 16) & 1u)) >> 16;
  return (unsigned short)u;
}

DEVINL s16x8 pack8(float4 a, float4 b) {
  s16x8 r;
  r[0] = (short)f2b(a.x); r[1] = (short)f2b(a.y);
  r[2] = (short)f2b(a.z); r[3] = (short)f2b(a.w);
  r[4] = (short)f2b(b.x); r[5] = (short)f2b(b.y);
  r[6] = (short)f2b(b.z); r[7] = (short)f2b(b.w);
  return r;
}

DEVINL f32x4 mfma16(s16x8 a, s16x8 b, f32x4 c) {
  return __builtin_amdgcn_mfma_f32_16x16x32_bf16(a, b, c, 0, 0, 0);
}

DEVINL void gload16(const void* g, void* l) {  // 16B global -> LDS direct
  __builtin_amdgcn_global_load_lds(
      (const __attribute__((address_space(1))) void*)g,
      (__attribute__((address_space(3))) void*)l, 16, 0, 0);
}

// ---------------------------------------------------------------------------
// 7 f32->bf16 converts in one launch. grid (2048, 7).
// ---------------------------------------------------------------------------
__global__ __launch_bounds__(256) void cvt7_k(
    const float* __restrict__ w0, const float* __restrict__ w1,
    const float* __restrict__ w2, const float* __restrict__ w3,
    const float* __restrict__ x0, const float* __restrict__ x1,
    const float* __restrict__ x2, unsigned short* __restrict__ dw,
    unsigned short* __restrict__ dwo, unsigned short* __restrict__ dx) {
  int z = blockIdx.y;
  const float* s;
  unsigned short* d;
  int n;
  if (z < 3)      { s = (z == 0) ? w0 : (z == 1) ? w1 : w2;
                    d = dw + (size_t)z * 1048576; n = 1048576; }
  else if (z == 3){ s = w3; d = dwo; n = 1048576; }
  else            { s = (z == 4) ? x0 : (z == 5) ? x1 : x2;
                    d = dx + (size_t)(z - 4) * 4194304; n = 4194304; }
  int i = (blockIdx.x * 256 + threadIdx.x) * 8;
  if (i < n) {
    float4 a = *(const float4*)(s + i);
    float4 b = *(const float4*)(s + i + 4);
    u16x8 o;
    o[0] = f2b(a.x); o[1] = f2b(a.y); o[2] = f2b(a.z); o[3] = f2b(a.w);
    o[4] = f2b(b.x); o[5] = f2b(b.y); o[6] = f2b(b.z); o[7] = f2b(b.w);
    *(u16x8*)(d + i) = o;
  }
}

// ---------------------------------------------------------------------------
// m97-style NT GEMM, 128x128 tile (q/k/v projections).
// ---------------------------------------------------------------------------
template<bool QKV>
__global__ __launch_bounds__(256) void gemm_bt(
    const unsigned short* __restrict__ Ab, const unsigned short* __restrict__ Bb,
    const float* __restrict__ b0, const float* __restrict__ b1,
    const float* __restrict__ b2, float* __restrict__ Cf,
    unsigned short* __restrict__ Cb) {
  __shared__ unsigned short lA[4096];   // [128][32] bf16, linear
  __shared__ unsigned short lB[4096];
  int z = QKV ? blockIdx.z : 0;
  const unsigned short* A = Ab + (size_t)z * 4194304;
  const unsigned short* B = Bb + (size_t)z * 1048576;
  const float* bias = (z == 0) ? b0 : (z == 1) ? b1 : b2;
  float* C = Cf + (size_t)z * 4194304;
  unsigned short* Cw = (QKV && z == 1) ? Cb : nullptr;

  int t = threadIdx.x, lane = t & 63, w = t >> 6;
  int m0 = blockIdx.y * 128, n0 = blockIdx.x * 128;
  int wm = (w >> 1) * 64, wn = (w & 1) * 64;
  int lr = lane & 15, g = lane >> 4, kg = g * 8, rb = g * 4;

  int srow = t >> 2, scol = (t & 3) * 8;
  const unsigned short* gA = A + (size_t)(m0 + srow) * 1024 + scol;
  const unsigned short* gB = B + (size_t)(n0 + srow) * 1024 + scol;
  unsigned short* dA = lA + w * 512;
  unsigned short* dB = lB + w * 512;

  f32x4 acc[4][4] = {};

  for (int k0 = 0; k0 < 1024; k0 += 32) {
    gload16(gA,             dA);
    gload16(gA + 64 * 1024, dA + 2048);
    gload16(gB,             dB);
    gload16(gB + 64 * 1024, dB + 2048);
    gA += 32; gB += 32;
    __syncthreads();
    s16x8 af[4], bf[4];
    #pragma unroll
    for (int i = 0; i < 4; i++)
      af[i] = *(const s16x8*)&lA[(wm + i * 16 + lr) * 32 + kg];
    #pragma unroll
    for (int j = 0; j < 4; j++)
      bf[j] = *(const s16x8*)&lB[(wn + j * 16 + lr) * 32 + kg];
    #pragma unroll
    for (int i = 0; i < 4; i++)
      #pragma unroll
      for (int j = 0; j < 4; j++)
        acc[i][j] = mfma16(af[i], bf[j], acc[i][j]);
    __syncthreads();
  }

  #pragma unroll
  for (int i = 0; i < 4; i++) {
    #pragma unroll
    for (int j = 0; j < 4; j++) {
      int col = n0 + wn + j * 16 + lr;
      float bv = bias[col];
      #pragma unroll
      for (int r = 0; r < 4; r++) {
        int row = m0 + wm + i * 16 + rb + r;
        float v = acc[i][j][r] + bv;
        size_t idx = (size_t)row * 1024 + col;
        C[idx] = v;
        if (Cw) Cw[idx] = f2b(v);
      }
    }
  }
}

// ---------------------------------------------------------------------------
// 128x64-tile GEMM for the out-projection: grid (16,32) = 512 blocks.
// ---------------------------------------------------------------------------
__global__ __launch_bounds__(256) void gemm_bt64(
    const unsigned short* __restrict__ Ab, const unsigned short* __restrict__ Bb,
    const float* __restrict__ bias, float* __restrict__ Cf) {
  __shared__ unsigned short lA[4096];   // [128][32]
  __shared__ unsigned short lB[2048];   // [64][32]
  int t = threadIdx.x, lane = t & 63, w = t >> 6;
  int m0 = blockIdx.y * 128, n0 = blockIdx.x * 64;
  int wm = (w >> 1) * 64, wn = (w & 1) * 32;
  int lr = lane & 15, g = lane >> 4, kg = g * 8, rb = g * 4;

  int srow = t >> 2, scol = (t & 3) * 8;
  unsigned short* dA = lA + w * 512;
  unsigned short* dB = lB + w * 512;

  const unsigned short* gA = Ab + (size_t)(m0 + srow) * 1024 + scol;
  const unsigned short* gB = Bb + (size_t)(n0 + srow) * 1024 + scol;
  f32x4 acc[4][2] = {};
  for (int k0 = 0; k0 < 1024; k0 += 32) {
    gload16(gA,             dA);
    gload16(gA + 64 * 1024, dA + 2048);
    gload16(gB,             dB);
    gA += 32; gB += 32;
    __syncthreads();
    s16x8 af[4], bf[2];
    #pragma unroll
    for (int i = 0; i < 4; i++)
      af[i] = *(const s16x8*)&lA[(wm + i * 16 + lr) * 32 + kg];
    #pragma unroll
    for (int j = 0; j < 2; j++)
      bf[j] = *(const s16x8*)&lB[(wn + j * 16 + lr) * 32 + kg];
    #pragma unroll
    for (int i = 0; i < 4; i++)
      #pragma unroll
      for (int j = 0; j < 2; j++)
        acc[i][j] = mfma16(af[i], bf[j], acc[i][j]);
    __syncthreads();
  }
  #pragma unroll
  for (int i = 0; i < 4; i++) {
    #pragma unroll
    for (int j = 0; j < 2; j++) {
      int col = n0 + wn + j * 16 + lr;
      float bv = bias[col];
      #pragma unroll
      for (int r = 0; r < 4; r++) {
        int row = m0 + wm + i * 16 + rb + r;
        Cf[(size_t)row * 1024 + col] = acc[i][j][r] + bv;
      }
    }
  }
}

// ---------------------------------------------------------------------------
// v (f32, [n][l][h*64+d]) -> vt (bf16, [n*16+h][d][l])  (unchanged)
// ---------------------------------------------------------------------------
__global__ __launch_bounds__(256) void transpose_v_k(
    const float* __restrict__ vf, unsigned short* __restrict__ vt) {
  __shared__ unsigned short tile[64][72];
  int nh = blockIdx.y, n = nh >> 4, h = nh & 15;
  int l0 = blockIdx.x * 64;
  int t = threadIdx.x;
  int lr = t >> 2;
  int dc = (t & 3) * 16;
  const float* src = vf + ((size_t)(n * 2048 + l0 + lr)) * 1024 + h * 64 + dc;
  float4 a = *(const float4*)(src);
  float4 b = *(const float4*)(src + 4);
  float4 c = *(const float4*)(src + 8);
  float4 e = *(const float4*)(src + 12);
  float vals[16] = {a.x, a.y, a.z, a.w, b.x, b.y, b.z, b.w,
                    c.x, c.y, c.z, c.w, e.x, e.y, e.z, e.w};
  #pragma unroll
  for (int j = 0; j < 16; j++) tile[dc + j][lr] = f2b(vals[j]);
  __syncthreads();
  int dr = t >> 2;
  int lc = (t & 3) * 16;
  unsigned short* dst = vt + ((size_t)nh * 64 + dr) * 2048 + l0 + lc;
  *(u16x8*)(dst)     = *(const u16x8*)&tile[dr][lc];
  *(u16x8*)(dst + 8) = *(const u16x8*)&tile[dr][lc + 8];
}

// ---------------------------------------------------------------------------
// attn_pv_k: COMPUTE-ONLY. tau-permuted zero-LDS swapped QK^T (round-8
// verified): lane (g,lr) holds S[q=lr][k = c0+(jk>>1)*32+g*8+(jk&1)*4+r]
// -> PV A-frags lane-local. No energy stores. Writes head bf16 + inv f32.
// Grid 2048 blocks x 128 thr (2 waves x 16 q-rows).
// ---------------------------------------------------------------------------
__global__ __launch_bounds__(128, 4) void attn_pv_k(
    const float* __restrict__ qf, const unsigned short* __restrict__ kb,
    const unsigned short* __restrict__ vt, unsigned short* __restrict__ head,
    float* __restrict__ invs) {
  int bid = blockIdx.x;
  int cid = (bid & 7) * 256 + (bid >> 3);    // XCD-contiguous remap (2048/8)
  int nh = cid >> 6, qt = cid & 63;
  int n = nh >> 4, h = nh & 15;
  int q0 = qt * 32;
  int t = threadIdx.x, w = t >> 6, lane = t & 63;
  int lr = lane & 15, g = lane >> 4, kg = g * 8, rb = g * 4;
  int wrow = w * 16;
  int kbase = ((lr >> 2) << 3) + (lr & 3);   // tau's lane-row component

  const float* qrow = qf + ((size_t)(n * 2048 + q0 + wrow + lr)) * 1024 + h * 64;
  s16x8 bq0 = pack8(*(const float4*)(qrow + kg), *(const float4*)(qrow + kg + 4));
  s16x8 bq1 = pack8(*(const float4*)(qrow + 32 + kg),
                    *(const float4*)(qrow + 32 + kg + 4));

  const unsigned short* Kb = kb + (size_t)n * (2048 * 1024) + h * 64;
  const unsigned short* Vb = vt + (size_t)nh * (64 * 2048);

  float lsum = 0.f;
  f32x4 acc_o[4] = {};

  for (int c0 = 0; c0 < 2048; c0 += 64) {
    s16x8 vv0[4], vv1[4];
    #pragma unroll
    for (int nf = 0; nf < 4; nf++) {
      const unsigned short* vp = Vb + (size_t)(nf * 16 + lr) * 2048 + c0 + kg;
      vv0[nf] = *(const s16x8*)(vp);
      vv1[nf] = *(const s16x8*)(vp + 32);
    }
    f32x4 s[4];
    #pragma unroll
    for (int jk = 0; jk < 4; jk++) {
      int kr = c0 + ((jk >> 1) << 5) + ((jk & 1) << 2) + kbase;
      const unsigned short* kp = Kb + (size_t)kr * 1024 + kg;
      s16x8 a0 = *(const s16x8*)kp;
      s16x8 a1 = *(const s16x8*)(kp + 32);
      f32x4 z = {};
      z = mfma16(a0, bq0, z);
      s[jk] = mfma16(a1, bq1, z);
    }
    float e[4][4];
    #pragma unroll
    for (int jk = 0; jk < 4; jk++)
      #pragma unroll
      for (int r = 0; r < 4; r++) {
        e[jk][r] = __expf(s[jk][r] * 0.125f);
        lsum += e[jk][r];
      }
    s16x8 pa0, pa1;
    #pragma unroll
    for (int r = 0; r < 4; r++) {
      pa0[r]     = (short)f2b(e[0][r]);
      pa0[r + 4] = (short)f2b(e[1][r]);
      pa1[r]     = (short)f2b(e[2][r]);
      pa1[r + 4] = (short)f2b(e[3][r]);
    }
    #pragma unroll
    for (int nf = 0; nf < 4; nf++) {
      acc_o[nf] = mfma16(pa0, vv0[nf], acc_o[nf]);
      acc_o[nf] = mfma16(pa1, vv1[nf], acc_o[nf]);
    }
  }

  // full row sum for q = q0+wrow+lr (4 lanes share lr)
  lsum += __shfl_xor(lsum, 16);
  lsum += __shfl_xor(lsum, 32);
  float inv = 1.0f / lsum;
  if (lane < 16) invs[(size_t)nh * 2048 + q0 + wrow + lr] = inv;
  float invr[4];
  #pragma unroll
  for (int r = 0; r < 4; r++) invr[r] = __shfl(inv, rb + r);

  unsigned short* hrow = head + ((size_t)(n * 2048 + q0 + wrow)) * 1024 + h * 64;
  #pragma unroll
  for (int nf = 0; nf < 4; nf++)
    #pragma unroll
    for (int r = 0; r < 4; r++)
      hrow[(size_t)(rb + r) * 1024 + nf * 16 + lr] = f2b(acc_o[nf][r] * invr[r]);
}

// ---------------------------------------------------------------------------
// attn_store_k: STREAM-ONLY. Recompute QK^T once; store energy AND attention
// with 1KB-contiguous NT row stores via a 16KB LDS stage.
// Unpermuted swapped mapping: s[r] = S[k=cb+jk*16+g*4+r][q=q0+lr].
// Stage [16 rows][256 cols] f32, phys col-quad = logical ^ ((row&7)).
// Grid 4096 blocks x 64 thr (1 wave, 16 q-rows, full 2048 cols).
// ---------------------------------------------------------------------------
__global__ __launch_bounds__(64) void attn_store_k(
    const float* __restrict__ qf, const unsigned short* __restrict__ kb,
    const float* __restrict__ invs, float* __restrict__ energy,
    float* __restrict__ attn) {
  __shared__ float stage[4096];              // 16 x 256 f32 = 16KB
  int bid = blockIdx.x;
  int cid = (bid & 7) * 512 + (bid >> 3);    // XCD-contiguous remap (4096/8)
  int nh = cid >> 7, qt = cid & 127;
  int n = nh >> 4, h = nh & 15;
  int q0 = qt * 16;
  int lane = threadIdx.x;
  int lr = lane & 15, g = lane >> 4, kg = g * 8, rb = g * 4;

  const float* qrow = qf + ((size_t)(n * 2048 + q0 + lr)) * 1024 + h * 64;
  s16x8 bq0 = pack8(*(const float4*)(qrow + kg), *(const float4*)(qrow + kg + 4));
  s16x8 bq1 = pack8(*(const float4*)(qrow + 32 + kg),
                    *(const float4*)(qrow + 32 + kg + 4));

  const unsigned short* Kb = kb + (size_t)n * (2048 * 1024) + h * 64;
  float* eblk = energy + (size_t)nh * (2048ull * 2048ull) + (size_t)q0 * 2048;
  float* ablk = attn + (size_t)nh * (2048ull * 2048ull) + (size_t)q0 * 2048;
  float invv = invs[(size_t)nh * 2048 + q0 + (lane & 15)];

  for (int c0 = 0; c0 < 2048; c0 += 256) {
    // fill stage: 4 chunks x 4 jk, C-layout -> swizzled [row][col]
    #pragma unroll
    for (int cc = 0; cc < 4; cc++) {
      #pragma unroll
      for (int jk = 0; jk < 4; jk++) {
        const unsigned short* kp =
            Kb + (size_t)(c0 + cc * 64 + jk * 16 + lr) * 1024 + kg;
        s16x8 a0 = *(const s16x8*)kp;
        s16x8 a1 = *(const s16x8*)(kp + 32);
        f32x4 z = {};
        z = mfma16(a0, bq0, z);
        f32x4 s = mfma16(a1, bq1, z);
        int col = cc * 64 + jk * 16 + rb;            // logical col (4-aligned)
        *(f32x4*)&stage[lr * 256 + (col ^ ((lr & 7) << 2))] = s;
      }
    }
    __syncthreads();   // lgkm drain before re-read (1 wave: cheap)
    // dump: row i, lane L covers cols 4L..4L+3 -> 1KB contiguous per store
    #pragma unroll
    for (int i = 0; i < 16; i++) {
      f32x4 ev = *(const f32x4*)&stage[i * 256 + ((lane * 4) ^ ((i & 7) << 2))];
      __builtin_nontemporal_store(
          ev, (f32x4*)(eblk + (size_t)i * 2048 + c0 + lane * 4));
      float iv = __shfl(invv, i);
      f32x4 av;
      av[0] = __expf(ev[0] * 0.125f) * iv;
      av[1] = __expf(ev[1] * 0.125f) * iv;
      av[2] = __expf(ev[2] * 0.125f) * iv;
      av[3] = __expf(ev[3] * 0.125f) * iv;
      __builtin_nontemporal_store(
          av, (f32x4*)(ablk + (size_t)i * 2048 + c0 + lane * 4));
    }
    __syncthreads();   // stage reuse guard
  }
}

// ---------------------------------------------------------------------------
extern "C" void kernel_launch(void* const* d_in, const int* in_sizes, int n_in,
                              void* d_out, int out_size, void* d_ws, size_t ws_size,
                              hipStream_t stream) {
  const float* Vin = (const float*)d_in[0];
  const float* Kin = (const float*)d_in[1];
  const float* Qin = (const float*)d_in[2];
  const float* Wq  = (const float*)d_in[3];
  const float* bq  = (const float*)d_in[4];
  const float* Wk  = (const float*)d_in[5];
  const float* bk  = (const float*)d_in[6];
  const float* Wv  = (const float*)d_in[7];
  const float* bv  = (const float*)d_in[8];
  const float* Wo  = (const float*)d_in[9];
  const float* bo  = (const float*)d_in[10];

  float* out    = (float*)d_out;
  float* qf     = out + 4194304;          // (4096,1024) f32; kf,vf follow
  float* energy = out + 16777216;         // (2,16,2048,2048) f32
  float* attn   = out + 150994944;

  unsigned short* vt = (unsigned short*)out;            // [nh][64][2048]
  unsigned short* kb = (unsigned short*)out + 4194304;
  unsigned short* wqkv = (unsigned short*)energy;
  unsigned short* xqkv = (unsigned short*)(energy + 2097152);
  // d_ws: head bf16 (8MB) + wob bf16 (2MB) + invs f32 (256KB)
  unsigned short* head = (unsigned short*)d_ws;
  unsigned short* wob  = head + 4194304;
  float* invs = (float*)(wob + 1048576);

  cvt7_k<<<dim3(2048, 7), 256, 0, stream>>>(
      Wq, Wk, Wv, Wo, Qin, Kin, Vin, wqkv, wob, xqkv);

  gemm_bt<true><<<dim3(8, 32, 3), 256, 0, stream>>>(
      xqkv, wqkv, bq, bk, bv, qf, kb);

  transpose_v_k<<<dim3(32, 32), 256, 0, stream>>>(qf + 8388608, vt);

  attn_pv_k<<<dim3(2048), 128, 0, stream>>>(qf, kb, vt, head, invs);

  attn_store_k<<<dim3(4096), 64, 0, stream>>>(qf, kb, invs, energy, attn);

  gemm_bt64<<<dim3(16, 32), 256, 0, stream>>>(head, wob, bo, out);
}